// Round 1
// baseline (1341.617 us; speedup 1.0000x reference)
//
#include <hip/hip_runtime.h>

// ---------------------------------------------------------------------------
// BertBiAttention baseline (fp32, vector-ALU GEMMs).
// B=16, S1=256 (vision), S2=512 (text), V_HID=1024, T_HID=768, BI_HID=1024,
// H=8, D=128.  All GEMM shapes are multiples of the 128x128x16 tile.
// ---------------------------------------------------------------------------

constexpr int BM = 128, BN = 128, BK = 16, PADF = 4;

// Generic batched GEMM:  C[m,n] = alpha * sum_k A[m,k] * B'[k,n] + bias[n]
//   TRANSB=false: B' = B (row-major [K,N], ldb)
//   TRANSB=true : B' = B^T (B row-major [N,K], ldb)   (used for Q @ K^T)
// Batch bz -> (bb = bz/Hd, hh = bz%Hd); each tensor offset bb*sb + hh*sh.
// bias indexed as bias[bb*bias_sb + n] (mask1/mask2 broadcast over rows).
template<bool TRANSB>
__global__ __launch_bounds__(256, 2)
void gemm_k(const float* __restrict__ A, const float* __restrict__ B,
            const float* __restrict__ bias, float* __restrict__ C,
            int M, int N, int K,
            int lda, int ldb, int ldc,
            long a_sb, long a_sh, long b_sb, long b_sh,
            long c_sb, long c_sh, long bias_sb,
            int Hd, float alpha)
{
    __shared__ float As[BK][BM + PADF];
    __shared__ float Bs[BK][BN + PADF];

    const int bz = blockIdx.z;
    const int bb = bz / Hd, hh = bz % Hd;
    A += (long)bb * a_sb + (long)hh * a_sh;
    B += (long)bb * b_sb + (long)hh * b_sh;
    C += (long)bb * c_sb + (long)hh * c_sh;

    const int m0 = blockIdx.y * BM;
    const int n0 = blockIdx.x * BN;

    const int t  = threadIdx.x;
    const int tx = t & 15;          // n-direction thread coord (16)
    const int ty = t >> 4;          // m-direction thread coord (16)

    // staging coords: A tile is 128 rows x 16 k  (2 float4 per thread)
    const int arow  = t >> 1;        // 0..127
    const int akcol = (t & 1) * 8;   // 0 or 8
    // B tile (NN): 16 k-rows x 128 n
    const int bkrow = t >> 4;        // 0..15
    const int bncol = (t & 15) * 8;  // 0..120

    float acc[8][8];
#pragma unroll
    for (int i = 0; i < 8; ++i)
#pragma unroll
        for (int j = 0; j < 8; ++j) acc[i][j] = 0.0f;

    for (int k0 = 0; k0 < K; k0 += BK) {
        // ---- stage A tile (transposed into As[k][m]) ----
        {
            const float* src = A + (long)(m0 + arow) * lda + (k0 + akcol);
            const float4 v0 = *(const float4*)(src);
            const float4 v1 = *(const float4*)(src + 4);
            As[akcol + 0][arow] = v0.x; As[akcol + 1][arow] = v0.y;
            As[akcol + 2][arow] = v0.z; As[akcol + 3][arow] = v0.w;
            As[akcol + 4][arow] = v1.x; As[akcol + 5][arow] = v1.y;
            As[akcol + 6][arow] = v1.z; As[akcol + 7][arow] = v1.w;
        }
        // ---- stage B tile ----
        if (!TRANSB) {
            const float* src = B + (long)(k0 + bkrow) * ldb + (n0 + bncol);
            const float4 v0 = *(const float4*)(src);
            const float4 v1 = *(const float4*)(src + 4);
            *(float4*)&Bs[bkrow][bncol]     = v0;
            *(float4*)&Bs[bkrow][bncol + 4] = v1;
        } else {
            const float* src = B + (long)(n0 + arow) * ldb + (k0 + akcol);
            const float4 v0 = *(const float4*)(src);
            const float4 v1 = *(const float4*)(src + 4);
            Bs[akcol + 0][arow] = v0.x; Bs[akcol + 1][arow] = v0.y;
            Bs[akcol + 2][arow] = v0.z; Bs[akcol + 3][arow] = v0.w;
            Bs[akcol + 4][arow] = v1.x; Bs[akcol + 5][arow] = v1.y;
            Bs[akcol + 6][arow] = v1.z; Bs[akcol + 7][arow] = v1.w;
        }
        __syncthreads();

        // ---- compute: 8x8 micro-tile, 4x4 at 4 corners ----
#pragma unroll
        for (int kk = 0; kk < BK; ++kk) {
            float ra[8], rb[8];
            const float4 a0 = *(const float4*)&As[kk][ty * 4];
            const float4 a1 = *(const float4*)&As[kk][64 + ty * 4];
            const float4 b0 = *(const float4*)&Bs[kk][tx * 4];
            const float4 b1 = *(const float4*)&Bs[kk][64 + tx * 4];
            ra[0]=a0.x; ra[1]=a0.y; ra[2]=a0.z; ra[3]=a0.w;
            ra[4]=a1.x; ra[5]=a1.y; ra[6]=a1.z; ra[7]=a1.w;
            rb[0]=b0.x; rb[1]=b0.y; rb[2]=b0.z; rb[3]=b0.w;
            rb[4]=b1.x; rb[5]=b1.y; rb[6]=b1.z; rb[7]=b1.w;
#pragma unroll
            for (int i = 0; i < 8; ++i)
#pragma unroll
                for (int j = 0; j < 8; ++j)
                    acc[i][j] = fmaf(ra[i], rb[j], acc[i][j]);
        }
        __syncthreads();
    }

    // ---- epilogue: C = alpha*acc + bias ----
    float bv[8];
#pragma unroll
    for (int jn = 0; jn < 2; ++jn)
#pragma unroll
        for (int j = 0; j < 4; ++j) {
            const int n = n0 + jn * 64 + tx * 4 + j;
            bv[jn * 4 + j] = bias ? bias[(long)bb * bias_sb + n] : 0.0f;
        }

#pragma unroll
    for (int im = 0; im < 2; ++im)
#pragma unroll
        for (int i = 0; i < 4; ++i) {
            const int m = m0 + im * 64 + ty * 4 + i;
            float* crow = C + (long)m * ldc;
#pragma unroll
            for (int jn = 0; jn < 2; ++jn) {
                float4 o;
                o.x = alpha * acc[im*4+i][jn*4+0] + bv[jn*4+0];
                o.y = alpha * acc[im*4+i][jn*4+1] + bv[jn*4+1];
                o.z = alpha * acc[im*4+i][jn*4+2] + bv[jn*4+2];
                o.w = alpha * acc[im*4+i][jn*4+3] + bv[jn*4+3];
                *(float4*)&crow[n0 + jn * 64 + tx * 4] = o;
            }
        }
}

// In-place row softmax; one wave (64 lanes) per row, 4 rows per block.
template<int L>
__global__ __launch_bounds__(256)
void softmax_rows(float* __restrict__ buf, int nrows)
{
    constexpr int PER = L / 64;      // 4 (L=256) or 8 (L=512)
    constexpr int NV4 = PER / 4;
    const int lane = threadIdx.x & 63;
    const int wv   = threadIdx.x >> 6;
    const long row = (long)blockIdx.x * 4 + wv;
    if (row >= nrows) return;
    float* p = buf + row * (long)L;

    float v[PER];
#pragma unroll
    for (int c = 0; c < NV4; ++c) {
        const float4 f = *(const float4*)&p[(c * 64 + lane) * 4];
        v[c*4+0]=f.x; v[c*4+1]=f.y; v[c*4+2]=f.z; v[c*4+3]=f.w;
    }
    float mx = v[0];
#pragma unroll
    for (int i = 1; i < PER; ++i) mx = fmaxf(mx, v[i]);
#pragma unroll
    for (int o = 32; o >= 1; o >>= 1) mx = fmaxf(mx, __shfl_xor(mx, o, 64));
    float s = 0.0f;
#pragma unroll
    for (int i = 0; i < PER; ++i) { v[i] = __expf(v[i] - mx); s += v[i]; }
#pragma unroll
    for (int o = 32; o >= 1; o >>= 1) s += __shfl_xor(s, o, 64);
    const float r = 1.0f / s;
#pragma unroll
    for (int c = 0; c < NV4; ++c) {
        float4 f;
        f.x = v[c*4+0]*r; f.y = v[c*4+1]*r; f.z = v[c*4+2]*r; f.w = v[c*4+3]*r;
        *(float4*)&p[(c * 64 + lane) * 4] = f;
    }
}

extern "C" void kernel_launch(void* const* d_in, const int* in_sizes, int n_in,
                              void* d_out, int out_size, void* d_ws, size_t ws_size,
                              hipStream_t stream)
{
    const float* in1   = (const float*)d_in[0];   // [16,256,1024]
    const float* mask1 = (const float*)d_in[1];   // [16,1,1,256]
    const float* in2   = (const float*)d_in[2];   // [16,512,768]
    const float* mask2 = (const float*)d_in[3];   // [16,1,1,512]
    const float* Wq1 = (const float*)d_in[4];  const float* bq1 = (const float*)d_in[5];
    const float* Wk1 = (const float*)d_in[6];  const float* bk1 = (const float*)d_in[7];
    const float* Wv1 = (const float*)d_in[8];  const float* bv1 = (const float*)d_in[9];
    const float* Wq2 = (const float*)d_in[10]; const float* bq2 = (const float*)d_in[11];
    const float* Wk2 = (const float*)d_in[12]; const float* bk2 = (const float*)d_in[13];
    const float* Wv2 = (const float*)d_in[14]; const float* bv2 = (const float*)d_in[15];

    constexpr int Bb = 16, S1 = 256, S2 = 512, VH = 1024, TH = 768,
                  BH = 1024, H = 8, D = 128;
    constexpr long M1 = (long)Bb * S1;   // 4096
    constexpr long M2 = (long)Bb * S2;   // 8192

    // Workspace (phased/aliased): peak 37,748,736 floats = 151 MB.
    //   phase1: rA=q2[8192x1024]  rB=k1[4096x1024]  rC=v1[4096x1024]
    //   phase2: rA=k2[8192x1024]  rB=v2[8192x1024]  rC=q1[4096x1024]
    //   rS: scores/probs (in-place softmax), 128*512*256 = 16.78M floats
    float* ws = (float*)d_ws;
    float* rA = ws;
    float* rB = rA + M2 * BH;
    float* rC = rB + M2 * BH;
    float* rS = rC + M1 * BH;

    const float scale = 0.088388347648318447f;  // 1/sqrt(128)
    const dim3 blk(256);

    // ================= phase 1: context1 = softmax(q2 k1^T) v1 =============
    // q2 = in2 @ Wq2 + bq2  -> rA
    gemm_k<false><<<dim3(BH/BN, M2/BM, 1), blk, 0, stream>>>(
        in2, Wq2, bq2, rA, (int)M2, BH, TH, TH, BH, BH,
        0,0, 0,0, 0,0, 0, 1, 1.0f);
    // k1 = in1 @ Wk1 + bk1 -> rB
    gemm_k<false><<<dim3(BH/BN, M1/BM, 1), blk, 0, stream>>>(
        in1, Wk1, bk1, rB, (int)M1, BH, VH, VH, BH, BH,
        0,0, 0,0, 0,0, 0, 1, 1.0f);
    // v1 = in1 @ Wv1 + bv1 -> rC
    gemm_k<false><<<dim3(BH/BN, M1/BM, 1), blk, 0, stream>>>(
        in1, Wv1, bv1, rC, (int)M1, BH, VH, VH, BH, BH,
        0,0, 0,0, 0,0, 0, 1, 1.0f);
    // scores1 = scale * q2 @ k1^T + mask1 -> rS  [B*H, 512, 256]
    gemm_k<true><<<dim3(S1/BN, S2/BM, Bb*H), blk, 0, stream>>>(
        rA, rB, mask1, rS, S2, S1, D, BH, BH, S1,
        (long)S2*BH, D, (long)S1*BH, D, (long)H*S2*S1, (long)S2*S1, S1,
        H, scale);
    softmax_rows<256><<<dim3(Bb*H*S2/4), blk, 0, stream>>>(rS, Bb*H*S2);
    // context1 = probs1 @ v1 -> d_out[0 ..]  [B,512,H,128]
    gemm_k<false><<<dim3(D/BN, S2/BM, Bb*H), blk, 0, stream>>>(
        rS, rC, nullptr, (float*)d_out, S2, D, S1, S1, BH, BH,
        (long)H*S2*S1, (long)S2*S1, (long)S1*BH, D, (long)S2*BH, D, 0,
        H, 1.0f);

    // ================= phase 2: context2 = softmax(q1 k2^T) v2 =============
    // q1 -> rC, k2 -> rA, v2 -> rB
    gemm_k<false><<<dim3(BH/BN, M1/BM, 1), blk, 0, stream>>>(
        in1, Wq1, bq1, rC, (int)M1, BH, VH, VH, BH, BH,
        0,0, 0,0, 0,0, 0, 1, 1.0f);
    gemm_k<false><<<dim3(BH/BN, M2/BM, 1), blk, 0, stream>>>(
        in2, Wk2, bk2, rA, (int)M2, BH, TH, TH, BH, BH,
        0,0, 0,0, 0,0, 0, 1, 1.0f);
    gemm_k<false><<<dim3(BH/BN, M2/BM, 1), blk, 0, stream>>>(
        in2, Wv2, bv2, rB, (int)M2, BH, TH, TH, BH, BH,
        0,0, 0,0, 0,0, 0, 1, 1.0f);
    // scores2 = scale * q1 @ k2^T + mask2 -> rS  [B*H, 256, 512]
    gemm_k<true><<<dim3(S2/BN, S1/BM, Bb*H), blk, 0, stream>>>(
        rC, rA, mask2, rS, S1, S2, D, BH, BH, S2,
        (long)S1*BH, D, (long)S2*BH, D, (long)H*S1*S2, (long)S1*S2, S2,
        H, scale);
    softmax_rows<512><<<dim3(Bb*H*S1/4), blk, 0, stream>>>(rS, Bb*H*S1);
    // context2 = probs2 @ v2 -> d_out + B*S2*BH  [B,256,H,128]
    gemm_k<false><<<dim3(D/BN, S1/BM, Bb*H), blk, 0, stream>>>(
        rS, rB, nullptr, (float*)d_out + (long)Bb*S2*BH, S1, D, S2, S2, BH, BH,
        (long)H*S1*S2, (long)S1*S2, (long)S2*BH, D, (long)S1*BH, D, 0,
        H, 1.0f);
}

// Round 2
// 669.853 us; speedup vs baseline: 2.0029x; 2.0029x over previous
//
#include <hip/hip_runtime.h>

// ---------------------------------------------------------------------------
// BertBiAttention via split-precision bf16 MFMA (x = hi + lo bf16;
// A*B = hi*hi + hi*lo + lo*hi, fp32 accumulate -> ~2^-17 per-product error).
// m97-style GEMM: 128x128 tile, BK=32, 4 waves, 16x16x32 MFMA,
// global_load_lds width-16 staging, LDS tiles [row][k] (k contiguous).
// ---------------------------------------------------------------------------

typedef unsigned short u16;
typedef unsigned int   u32;
typedef short v8s __attribute__((ext_vector_type(8)));   // 8 bf16 (4 VGPRs)
typedef float v4f __attribute__((ext_vector_type(4)));   // MFMA acc

struct alignas(8) us4 { u16 x, y, z, w; };

__device__ __forceinline__ u16 f2bf(float x) {           // RNE fp32->bf16
    u32 u = __float_as_uint(x);
    u += 0x7fffu + ((u >> 16) & 1u);
    return (u16)(u >> 16);
}
__device__ __forceinline__ float bf2f(u16 h) { return __uint_as_float(((u32)h) << 16); }

// async global->LDS, 16B per lane; LDS dest = wave-uniform base + lane*16
#define GLL16(g, l) __builtin_amdgcn_global_load_lds(                          \
    (const __attribute__((address_space(1))) u32*)(g),                         \
    (__attribute__((address_space(3))) u32*)(l), 16, 0, 0)

constexpr int BM = 128, BN = 128, BK = 32;

// ---------------------------------------------------------------------------
// convert fp32 -> (hi, lo) bf16 planes, elementwise
__global__ __launch_bounds__(256)
void cvt_split(const float* __restrict__ in, u16* __restrict__ hi,
               u16* __restrict__ lo, long n)
{
    long i = ((long)blockIdx.x * 256 + threadIdx.x) * 4;
    if (i >= n) return;
    float4 v = *(const float4*)&in[i];
    u16 h0 = f2bf(v.x), h1 = f2bf(v.y), h2 = f2bf(v.z), h3 = f2bf(v.w);
    us4 h = {h0, h1, h2, h3};
    us4 l = {f2bf(v.x - bf2f(h0)), f2bf(v.y - bf2f(h1)),
             f2bf(v.z - bf2f(h2)), f2bf(v.w - bf2f(h3))};
    *(us4*)&hi[i] = h;
    *(us4*)&lo[i] = l;
}

// convert + transpose: W fp32 [K][N] -> hiT/loT bf16 [N][K]  (64x64 LDS tiles)
__global__ __launch_bounds__(256)
void cvt_split_T(const float* __restrict__ in, u16* __restrict__ hiT,
                 u16* __restrict__ loT, int Kd, int Nd)
{
    __shared__ float t[64][65];
    const int bk = blockIdx.y * 64, bn = blockIdx.x * 64;
    const int r0 = threadIdx.x >> 4;        // 0..15
    const int c4 = (threadIdx.x & 15) * 4;  // 0..60
#pragma unroll
    for (int rr = 0; rr < 64; rr += 16) {
        float4 v = *(const float4*)&in[(long)(bk + rr + r0) * Nd + bn + c4];
        t[rr + r0][c4 + 0] = v.x; t[rr + r0][c4 + 1] = v.y;
        t[rr + r0][c4 + 2] = v.z; t[rr + r0][c4 + 3] = v.w;
    }
    __syncthreads();
#pragma unroll
    for (int rr = 0; rr < 64; rr += 16) {
        const int n = rr + r0;
        float x0 = t[c4 + 0][n], x1 = t[c4 + 1][n], x2 = t[c4 + 2][n], x3 = t[c4 + 3][n];
        u16 h0 = f2bf(x0), h1 = f2bf(x1), h2 = f2bf(x2), h3 = f2bf(x3);
        us4 h = {h0, h1, h2, h3};
        us4 l = {f2bf(x0 - bf2f(h0)), f2bf(x1 - bf2f(h1)),
                 f2bf(x2 - bf2f(h2)), f2bf(x3 - bf2f(h3))};
        long o = (long)(bn + n) * Kd + bk + c4;
        *(us4*)&hiT[o] = h;
        *(us4*)&loT[o] = l;
    }
}

// ---------------------------------------------------------------------------
// Split-bf16 MFMA GEMM.  C[m,n] = sum_k A[m,k]*B'[n,k]  (+ epilogue)
// A planes row-major [M][K] (lda), B planes row-major [N][K] (ldb).
// Batch z -> bb=z/Hd, hh=z%Hd; plane += bb*sb + hh*sh (u16 elements).
// EPI: 0 = +bias, write hi/lo row-major [M][N]          (q,k projections)
//      1 = +bias, write hi/lo transposed [bb][n][s]     (v projection; Sv = rows/batch)
//      2 = alpha*acc + mask[(bb+bb0)*N + n], fp32 out   (scores)
//      3 = fp32 out at [(bb*Sq+m)*1024 + hh*128 + n]    (probs @ V)
template<int EPI>
__global__ __launch_bounds__(256, 2)
void mm_split(const u16* __restrict__ Ahi, const u16* __restrict__ Alo,
              const u16* __restrict__ Bhi, const u16* __restrict__ Blo,
              const float* __restrict__ bias, float* __restrict__ Cf,
              u16* __restrict__ Chi, u16* __restrict__ Clo,
              int K, int lda, int ldb,
              long a_sb, long a_sh, long b_sb, long b_sh,
              int Hd, int Sv, int bb0, float alpha)
{
    __shared__ u16 As[2][BM * BK];   // [plane hi/lo][m*32 + k]
    __shared__ u16 Bs[2][BN * BK];   // [plane hi/lo][n*32 + k]

    const int z  = blockIdx.z;
    const int bb = z / Hd, hh = z % Hd;
    Ahi += (long)bb * a_sb + (long)hh * a_sh;
    Alo += (long)bb * a_sb + (long)hh * a_sh;
    Bhi += (long)bb * b_sb + (long)hh * b_sh;
    Blo += (long)bb * b_sb + (long)hh * b_sh;

    const int m0 = blockIdx.y * BM, n0 = blockIdx.x * BN;
    const int lane = threadIdx.x & 63;
    const int w    = threadIdx.x >> 6;      // wave 0..3
    const int wm   = w >> 1, wn = w & 1;    // 2x2 wave grid, 64x64 each

    v4f acc[4][4];
#pragma unroll
    for (int i = 0; i < 4; ++i)
#pragma unroll
        for (int j = 0; j < 4; ++j) acc[i][j] = (v4f){0.f, 0.f, 0.f, 0.f};

    for (int k0 = 0; k0 < K; k0 += BK) {
        // ---- stage: 4 planes x 8KB; chunk c(0..511): row=c>>2, kcol16=c&3 ----
#pragma unroll
        for (int h = 0; h < 2; ++h) {
            const int c    = h * 256 + w * 64 + lane;
            const int row  = c >> 2, kc = c & 3;
            const int lbase = (h * 256 + w * 64) * 8;     // u16 index (lane0 chunk)
            const long ga = (long)(m0 + row) * lda + k0 + kc * 8;
            const long gb = (long)(n0 + row) * ldb + k0 + kc * 8;
            GLL16(Ahi + ga, &As[0][lbase]);
            GLL16(Alo + ga, &As[1][lbase]);
            GLL16(Bhi + gb, &Bs[0][lbase]);
            GLL16(Blo + gb, &Bs[1][lbase]);
        }
        __syncthreads();

        // ---- fragments: lane&15 = m/n in tile, lane>>4 = k-quad (8 bf16) ----
        const int fr = lane & 15, fq = lane >> 4;
        v8s ah[4], al[4], bh[4], bl[4];
#pragma unroll
        for (int tmi = 0; tmi < 4; ++tmi) {
            const int off = (wm * 64 + tmi * 16 + fr) * BK + fq * 8;
            ah[tmi] = *(const v8s*)&As[0][off];
            al[tmi] = *(const v8s*)&As[1][off];
        }
#pragma unroll
        for (int tni = 0; tni < 4; ++tni) {
            const int off = (wn * 64 + tni * 16 + fr) * BK + fq * 8;
            bh[tni] = *(const v8s*)&Bs[0][off];
            bl[tni] = *(const v8s*)&Bs[1][off];
        }
#pragma unroll
        for (int tmi = 0; tmi < 4; ++tmi)
#pragma unroll
            for (int tni = 0; tni < 4; ++tni) {
                acc[tmi][tni] = __builtin_amdgcn_mfma_f32_16x16x32_bf16(
                    ah[tmi], bh[tni], acc[tmi][tni], 0, 0, 0);
                acc[tmi][tni] = __builtin_amdgcn_mfma_f32_16x16x32_bf16(
                    ah[tmi], bl[tni], acc[tmi][tni], 0, 0, 0);
                acc[tmi][tni] = __builtin_amdgcn_mfma_f32_16x16x32_bf16(
                    al[tmi], bh[tni], acc[tmi][tni], 0, 0, 0);
            }
        __syncthreads();
    }

    // ---- epilogue; C layout: col = lane&15, row = (lane>>4)*4 + reg ----
    const int col = lane & 15, qrow = (lane >> 4) * 4;
    const int Nld = gridDim.x * BN;

    if (EPI == 0) {          // q/k projection: bias + hi/lo row-major
#pragma unroll
        for (int tmi = 0; tmi < 4; ++tmi) {
            const int mb = m0 + wm * 64 + tmi * 16 + qrow;
#pragma unroll
            for (int tni = 0; tni < 4; ++tni) {
                const int n = n0 + wn * 64 + tni * 16 + col;
                const float bv = bias[n];
#pragma unroll
                for (int i = 0; i < 4; ++i) {
                    const float v = acc[tmi][tni][i] + bv;
                    const u16 h = f2bf(v);
                    const long o = (long)(mb + i) * Nld + n;
                    Chi[o] = h;
                    Clo[o] = f2bf(v - bf2f(h));
                }
            }
        }
    } else if (EPI == 1) {   // v projection: bias + hi/lo transposed [bb][n][s]
#pragma unroll
        for (int tmi = 0; tmi < 4; ++tmi) {
            const int mb  = m0 + wm * 64 + tmi * 16 + qrow;
            const int bbv = mb / Sv, s = mb % Sv;
#pragma unroll
            for (int tni = 0; tni < 4; ++tni) {
                const int n = n0 + wn * 64 + tni * 16 + col;
                const float bv = bias[n];
                u16 hv[4], lv[4];
#pragma unroll
                for (int i = 0; i < 4; ++i) {
                    const float v = acc[tmi][tni][i] + bv;
                    hv[i] = f2bf(v);
                    lv[i] = f2bf(v - bf2f(hv[i]));
                }
                const long o = (long)bbv * 1024 * Sv + (long)n * Sv + s;
                *(us4*)&Chi[o] = (us4){hv[0], hv[1], hv[2], hv[3]};
                *(us4*)&Clo[o] = (us4){lv[0], lv[1], lv[2], lv[3]};
            }
        }
    } else if (EPI == 2) {   // scores: alpha*acc + mask, fp32
        const int Msub = gridDim.y * BM;
        const long cz = (long)z * Msub * Nld;
#pragma unroll
        for (int tmi = 0; tmi < 4; ++tmi) {
            const int mb = m0 + wm * 64 + tmi * 16 + qrow;
#pragma unroll
            for (int tni = 0; tni < 4; ++tni) {
                const int n = n0 + wn * 64 + tni * 16 + col;
                const float mk = bias[(long)(bb + bb0) * Nld + n];
#pragma unroll
                for (int i = 0; i < 4; ++i)
                    Cf[cz + (long)(mb + i) * Nld + n] = alpha * acc[tmi][tni][i] + mk;
            }
        }
    } else {                 // PV: fp32 -> d_out [bb*Sq+m][1024], col hh*128+n
        const int Sq = gridDim.y * BM;
#pragma unroll
        for (int tmi = 0; tmi < 4; ++tmi) {
            const int mb = m0 + wm * 64 + tmi * 16 + qrow;
#pragma unroll
            for (int tni = 0; tni < 4; ++tni) {
                const int n = n0 + wn * 64 + tni * 16 + col;
#pragma unroll
                for (int i = 0; i < 4; ++i)
                    Cf[(long)(bb * Sq + mb + i) * 1024 + hh * 128 + n] = acc[tmi][tni][i];
            }
        }
    }
}

// ---------------------------------------------------------------------------
// row softmax: fp32 scores in, bf16 hi/lo probs out; 1 wave/row, 4 rows/block
template<int L>
__global__ __launch_bounds__(256)
void softmax_split(const float* __restrict__ sc, u16* __restrict__ phi,
                   u16* __restrict__ plo, int nrows)
{
    constexpr int PER = L / 64, NV4 = PER / 4;
    const int lane = threadIdx.x & 63, wv = threadIdx.x >> 6;
    const long row = (long)blockIdx.x * 4 + wv;
    if (row >= nrows) return;
    const float* p = sc + row * (long)L;

    float v[PER];
#pragma unroll
    for (int c = 0; c < NV4; ++c) {
        float4 f = *(const float4*)&p[(c * 64 + lane) * 4];
        v[c*4+0] = f.x; v[c*4+1] = f.y; v[c*4+2] = f.z; v[c*4+3] = f.w;
    }
    float mx = v[0];
#pragma unroll
    for (int i = 1; i < PER; ++i) mx = fmaxf(mx, v[i]);
#pragma unroll
    for (int o = 32; o >= 1; o >>= 1) mx = fmaxf(mx, __shfl_xor(mx, o, 64));
    float s = 0.f;
#pragma unroll
    for (int i = 0; i < PER; ++i) { v[i] = __expf(v[i] - mx); s += v[i]; }
#pragma unroll
    for (int o = 32; o >= 1; o >>= 1) s += __shfl_xor(s, o, 64);
    const float r = 1.0f / s;
#pragma unroll
    for (int c = 0; c < NV4; ++c) {
        u16 hv[4], lv[4];
#pragma unroll
        for (int j = 0; j < 4; ++j) {
            const float x = v[c*4+j] * r;
            hv[j] = f2bf(x);
            lv[j] = f2bf(x - bf2f(hv[j]));
        }
        const long o = row * (long)L + (c * 64 + lane) * 4;
        *(us4*)&phi[o] = (us4){hv[0], hv[1], hv[2], hv[3]};
        *(us4*)&plo[o] = (us4){lv[0], lv[1], lv[2], lv[3]};
    }
}

// ---------------------------------------------------------------------------
extern "C" void kernel_launch(void* const* d_in, const int* in_sizes, int n_in,
                              void* d_out, int out_size, void* d_ws, size_t ws_size,
                              hipStream_t stream)
{
    const float* in1   = (const float*)d_in[0];
    const float* mask1 = (const float*)d_in[1];
    const float* in2   = (const float*)d_in[2];
    const float* mask2 = (const float*)d_in[3];
    const float* Wq1 = (const float*)d_in[4];  const float* bq1 = (const float*)d_in[5];
    const float* Wk1 = (const float*)d_in[6];  const float* bk1 = (const float*)d_in[7];
    const float* Wv1 = (const float*)d_in[8];  const float* bv1 = (const float*)d_in[9];
    const float* Wq2 = (const float*)d_in[10]; const float* bq2 = (const float*)d_in[11];
    const float* Wk2 = (const float*)d_in[12]; const float* bk2 = (const float*)d_in[13];
    const float* Wv2 = (const float*)d_in[14]; const float* bv2 = (const float*)d_in[15];

    constexpr int Bb = 16, S1 = 256, S2 = 512, VH = 1024, TH = 768, H = 8;
    constexpr long M1 = (long)Bb * S1, M2 = (long)Bb * S2;
    const float scale = 0.088388347648318447f;   // 1/sqrt(128)

    // ---- workspace layout (bytes, 16B aligned) ----
    char* W = (char*)d_ws;
    size_t o = 0;
    auto alloc = [&](size_t sz) { size_t r = o; o = (o + sz + 15) & ~(size_t)15; return r; };
    const size_t P_IN1 = M1 * VH * 2, P_IN2 = M2 * TH * 2;       // plane bytes
    const size_t P_W1 = (size_t)VH * 1024 * 2, P_W2 = (size_t)TH * 1024 * 2;
    const size_t o_i1h = alloc(P_IN1), o_i1l = alloc(P_IN1);
    const size_t o_i2h = alloc(P_IN2), o_i2l = alloc(P_IN2);
    const size_t o_wq1h = alloc(P_W1), o_wq1l = alloc(P_W1);
    const size_t o_wk1h = alloc(P_W1), o_wk1l = alloc(P_W1);
    const size_t o_wv1h = alloc(P_W1), o_wv1l = alloc(P_W1);
    const size_t o_wq2h = alloc(P_W2), o_wq2l = alloc(P_W2);
    const size_t o_wk2h = alloc(P_W2), o_wk2l = alloc(P_W2);
    const size_t o_wv2h = alloc(P_W2), o_wv2l = alloc(P_W2);
    const size_t QKV = 83886080;                  // max(phase1 67MB, phase2 84MB)
    const size_t o_qkv = alloc(QKV);
    // attention chunking over batch to fit ws
    const size_t fixed = o;
    int Bc = 16;
    while (Bc > 1 && fixed + (size_t)Bc * 8388608 > ws_size) Bc >>= 1;
    const size_t o_sc = alloc((size_t)Bc * 4194304);
    const size_t o_ph = alloc((size_t)Bc * 2097152);
    const size_t o_pl = alloc((size_t)Bc * 2097152);
    auto U = [&](size_t off) { return (u16*)(W + off); };
    float* scf = (float*)(W + o_sc);
    float* out = (float*)d_out;

    // ---- converts ----
    cvt_split<<<dim3((unsigned)(M1 * VH / 1024)), 256, 0, stream>>>(in1, U(o_i1h), U(o_i1l), M1 * VH);
    cvt_split<<<dim3((unsigned)(M2 * TH / 1024)), 256, 0, stream>>>(in2, U(o_i2h), U(o_i2l), M2 * TH);
    cvt_split_T<<<dim3(16, 16), 256, 0, stream>>>(Wq1, U(o_wq1h), U(o_wq1l), VH, 1024);
    cvt_split_T<<<dim3(16, 16), 256, 0, stream>>>(Wk1, U(o_wk1h), U(o_wk1l), VH, 1024);
    cvt_split_T<<<dim3(16, 16), 256, 0, stream>>>(Wv1, U(o_wv1h), U(o_wv1l), VH, 1024);
    cvt_split_T<<<dim3(16, 12), 256, 0, stream>>>(Wq2, U(o_wq2h), U(o_wq2l), TH, 1024);
    cvt_split_T<<<dim3(16, 12), 256, 0, stream>>>(Wk2, U(o_wk2h), U(o_wk2l), TH, 1024);
    cvt_split_T<<<dim3(16, 12), 256, 0, stream>>>(Wv2, U(o_wv2h), U(o_wv2l), TH, 1024);

    const dim3 blk(256);

    // ================= phase 1: context1 = softmax(q2 k1^T + m1) v1 =========
    u16 *q2h = U(o_qkv),            *q2l = U(o_qkv + 16777216);
    u16 *k1h = U(o_qkv + 33554432), *k1l = U(o_qkv + 41943040);
    u16 *v1h = U(o_qkv + 50331648), *v1l = U(o_qkv + 58720256);
    mm_split<0><<<dim3(8, 64, 1), blk, 0, stream>>>(U(o_i2h), U(o_i2l), U(o_wq2h), U(o_wq2l),
        bq2, nullptr, q2h, q2l, TH, TH, TH, 0, 0, 0, 0, 1, 0, 0, 1.f);
    mm_split<0><<<dim3(8, 32, 1), blk, 0, stream>>>(U(o_i1h), U(o_i1l), U(o_wk1h), U(o_wk1l),
        bk1, nullptr, k1h, k1l, VH, VH, VH, 0, 0, 0, 0, 1, 0, 0, 1.f);
    mm_split<1><<<dim3(8, 32, 1), blk, 0, stream>>>(U(o_i1h), U(o_i1l), U(o_wv1h), U(o_wv1l),
        bv1, nullptr, v1h, v1l, VH, VH, VH, 0, 0, 0, 0, 1, S1, 0, 1.f);
    for (int b0 = 0; b0 < Bb; b0 += Bc) {
        mm_split<2><<<dim3(S1 / BN, S2 / BM, Bc * H), blk, 0, stream>>>(
            q2h + (long)b0 * S2 * 1024, q2l + (long)b0 * S2 * 1024,
            k1h + (long)b0 * S1 * 1024, k1l + (long)b0 * S1 * 1024,
            mask1, scf, nullptr, nullptr, 128, 1024, 1024,
            (long)S2 * 1024, 128, (long)S1 * 1024, 128, H, 0, b0, scale);
        softmax_split<256><<<dim3(Bc * H * S2 / 4), blk, 0, stream>>>(
            scf, U(o_ph), U(o_pl), Bc * H * S2);
        mm_split<3><<<dim3(1, S2 / BM, Bc * H), blk, 0, stream>>>(
            U(o_ph), U(o_pl),
            v1h + (long)b0 * 1024 * S1, v1l + (long)b0 * 1024 * S1,
            nullptr, out + (long)b0 * S2 * 1024, nullptr, nullptr,
            S1, S1, S1, (long)H * S2 * S1, (long)S2 * S1,
            (long)1024 * S1, (long)128 * S1, H, 0, 0, 1.f);
    }

    // ================= phase 2: context2 = softmax(q1 k2^T + m2) v2 =========
    u16 *q1h = U(o_qkv),            *q1l = U(o_qkv + 8388608);
    u16 *k2h = U(o_qkv + 16777216), *k2l = U(o_qkv + 33554432);
    u16 *v2h = U(o_qkv + 50331648), *v2l = U(o_qkv + 67108864);
    mm_split<0><<<dim3(8, 32, 1), blk, 0, stream>>>(U(o_i1h), U(o_i1l), U(o_wq1h), U(o_wq1l),
        bq1, nullptr, q1h, q1l, VH, VH, VH, 0, 0, 0, 0, 1, 0, 0, 1.f);
    mm_split<0><<<dim3(8, 64, 1), blk, 0, stream>>>(U(o_i2h), U(o_i2l), U(o_wk2h), U(o_wk2l),
        bk2, nullptr, k2h, k2l, TH, TH, TH, 0, 0, 0, 0, 1, 0, 0, 1.f);
    mm_split<1><<<dim3(8, 64, 1), blk, 0, stream>>>(U(o_i2h), U(o_i2l), U(o_wv2h), U(o_wv2l),
        bv2, nullptr, v2h, v2l, TH, TH, TH, 0, 0, 0, 0, 1, S2, 0, 1.f);
    float* out2 = out + M2 * 1024;
    for (int b0 = 0; b0 < Bb; b0 += Bc) {
        mm_split<2><<<dim3(S2 / BN, S1 / BM, Bc * H), blk, 0, stream>>>(
            q1h + (long)b0 * S1 * 1024, q1l + (long)b0 * S1 * 1024,
            k2h + (long)b0 * S2 * 1024, k2l + (long)b0 * S2 * 1024,
            mask2, scf, nullptr, nullptr, 128, 1024, 1024,
            (long)S1 * 1024, 128, (long)S2 * 1024, 128, H, 0, b0, scale);
        softmax_split<512><<<dim3(Bc * H * S1 / 4), blk, 0, stream>>>(
            scf, U(o_ph), U(o_pl), Bc * H * S1);
        mm_split<3><<<dim3(1, S1 / BM, Bc * H), blk, 0, stream>>>(
            U(o_ph), U(o_pl),
            v2h + (long)b0 * 1024 * S2, v2l + (long)b0 * 1024 * S2,
            nullptr, out2 + (long)b0 * S1 * 1024, nullptr, nullptr,
            S2, S2, S2, (long)H * S1 * S2, (long)S1 * S2,
            (long)1024 * S2, (long)128 * S2, H, 0, 0, 1.f);
    }
}

// Round 3
// 470.669 us; speedup vs baseline: 2.8504x; 1.4232x over previous
//
#include <hip/hip_runtime.h>

// ---------------------------------------------------------------------------
// BertBiAttention: split-bf16 MFMA projections (concat weights, 2 GEMMs) +
// fused flash attention (split-bf16 QK^T, bf16 P/V, online softmax).
// ---------------------------------------------------------------------------

typedef unsigned short u16;
typedef unsigned int   u32;
typedef short v8s __attribute__((ext_vector_type(8)));   // 8 bf16
typedef float v4f __attribute__((ext_vector_type(4)));   // MFMA acc

struct alignas(8) us4 { u16 x, y, z, w; };

__device__ __forceinline__ u16 f2bf(float x) {           // RNE fp32->bf16
    u32 u = __float_as_uint(x);
    u += 0x7fffu + ((u >> 16) & 1u);
    return (u16)(u >> 16);
}
__device__ __forceinline__ float bf2f(u16 h) { return __uint_as_float(((u32)h) << 16); }

#define GLL16(g, l) __builtin_amdgcn_global_load_lds(                          \
    (const __attribute__((address_space(1))) u32*)(g),                         \
    (__attribute__((address_space(3))) u32*)(l), 16, 0, 0)

#define MFMA_BF16 __builtin_amdgcn_mfma_f32_16x16x32_bf16

// ---------------------------------------------------------------------------
__global__ __launch_bounds__(256)
void cvt_split(const float* __restrict__ in, u16* __restrict__ hi,
               u16* __restrict__ lo, long n)
{
    long i = ((long)blockIdx.x * 256 + threadIdx.x) * 4;
    if (i >= n) return;
    float4 v = *(const float4*)&in[i];
    u16 h0 = f2bf(v.x), h1 = f2bf(v.y), h2 = f2bf(v.z), h3 = f2bf(v.w);
    us4 h = {h0, h1, h2, h3};
    us4 l = {f2bf(v.x - bf2f(h0)), f2bf(v.y - bf2f(h1)),
             f2bf(v.z - bf2f(h2)), f2bf(v.w - bf2f(h3))};
    *(us4*)&hi[i] = h;
    *(us4*)&lo[i] = l;
}

// W fp32 [K][N] -> hiT/loT bf16 [N][K]
__global__ __launch_bounds__(256)
void cvt_split_T(const float* __restrict__ in, u16* __restrict__ hiT,
                 u16* __restrict__ loT, int Kd, int Nd)
{
    __shared__ float t[64][65];
    const int bk = blockIdx.y * 64, bn = blockIdx.x * 64;
    const int r0 = threadIdx.x >> 4;
    const int c4 = (threadIdx.x & 15) * 4;
#pragma unroll
    for (int rr = 0; rr < 64; rr += 16) {
        float4 v = *(const float4*)&in[(long)(bk + rr + r0) * Nd + bn + c4];
        t[rr + r0][c4 + 0] = v.x; t[rr + r0][c4 + 1] = v.y;
        t[rr + r0][c4 + 2] = v.z; t[rr + r0][c4 + 3] = v.w;
    }
    __syncthreads();
#pragma unroll
    for (int rr = 0; rr < 64; rr += 16) {
        const int n = rr + r0;
        float x0 = t[c4 + 0][n], x1 = t[c4 + 1][n], x2 = t[c4 + 2][n], x3 = t[c4 + 3][n];
        u16 h0 = f2bf(x0), h1 = f2bf(x1), h2 = f2bf(x2), h3 = f2bf(x3);
        us4 h = {h0, h1, h2, h3};
        us4 l = {f2bf(x0 - bf2f(h0)), f2bf(x1 - bf2f(h1)),
                 f2bf(x2 - bf2f(h2)), f2bf(x3 - bf2f(h3))};
        long o = (long)(bn + n) * Kd + bk + c4;
        *(us4*)&hiT[o] = h;
        *(us4*)&loT[o] = l;
    }
}

// ---------------------------------------------------------------------------
// Projection GEMM, concat weights: A [M][K] planes, B [3072][K] planes.
// seg = n0>>10: 0 -> q hi/lo [M][1024]; 1 -> k hi/lo [M][1024];
//               2 -> v bf16 transposed [b][1024][S].
__global__ __launch_bounds__(256, 2)
void mm_proj(const u16* __restrict__ Ah, const u16* __restrict__ Al,
             const u16* __restrict__ Bh, const u16* __restrict__ Bl,
             const float* __restrict__ bq, const float* __restrict__ bk,
             const float* __restrict__ bv,
             u16* __restrict__ qh, u16* __restrict__ ql,
             u16* __restrict__ kh, u16* __restrict__ kl,
             u16* __restrict__ vt, int K, int S)
{
    __shared__ u16 As[2][128 * 32];
    __shared__ u16 Bs[2][128 * 32];

    const int m0 = blockIdx.y * 128, n0 = blockIdx.x * 128;
    const int lane = threadIdx.x & 63;
    const int w    = threadIdx.x >> 6;
    const int wm   = w >> 1, wn = w & 1;

    v4f acc[4][4];
#pragma unroll
    for (int i = 0; i < 4; ++i)
#pragma unroll
        for (int j = 0; j < 4; ++j) acc[i][j] = (v4f){0.f, 0.f, 0.f, 0.f};

    for (int k0 = 0; k0 < K; k0 += 32) {
#pragma unroll
        for (int h = 0; h < 2; ++h) {
            const int c = h * 256 + w * 64 + lane;
            const int row = c >> 2, kc = c & 3;
            const int lbase = (h * 256 + w * 64) * 8;
            const long ga = (long)(m0 + row) * K + k0 + kc * 8;
            const long gb = (long)(n0 + row) * K + k0 + kc * 8;
            GLL16(Ah + ga, &As[0][lbase]);
            GLL16(Al + ga, &As[1][lbase]);
            GLL16(Bh + gb, &Bs[0][lbase]);
            GLL16(Bl + gb, &Bs[1][lbase]);
        }
        __syncthreads();

        const int fr = lane & 15, fq = lane >> 4;
        v8s ah[4], al[4], bh[4], bl[4];
#pragma unroll
        for (int tmi = 0; tmi < 4; ++tmi) {
            const int off = (wm * 64 + tmi * 16 + fr) * 32 + fq * 8;
            ah[tmi] = *(const v8s*)&As[0][off];
            al[tmi] = *(const v8s*)&As[1][off];
        }
#pragma unroll
        for (int tni = 0; tni < 4; ++tni) {
            const int off = (wn * 64 + tni * 16 + fr) * 32 + fq * 8;
            bh[tni] = *(const v8s*)&Bs[0][off];
            bl[tni] = *(const v8s*)&Bs[1][off];
        }
#pragma unroll
        for (int tmi = 0; tmi < 4; ++tmi)
#pragma unroll
            for (int tni = 0; tni < 4; ++tni) {
                acc[tmi][tni] = MFMA_BF16(ah[tmi], bh[tni], acc[tmi][tni], 0, 0, 0);
                acc[tmi][tni] = MFMA_BF16(ah[tmi], bl[tni], acc[tmi][tni], 0, 0, 0);
                acc[tmi][tni] = MFMA_BF16(al[tmi], bh[tni], acc[tmi][tni], 0, 0, 0);
            }
        __syncthreads();
    }

    const int col = lane & 15, qrow = (lane >> 4) * 4;
    const int seg = n0 >> 10, nbase = n0 & 1023;

    if (seg < 2) {
        const float* bias = seg == 0 ? bq : bk;
        u16* Ch = seg == 0 ? qh : kh;
        u16* Cl = seg == 0 ? ql : kl;
#pragma unroll
        for (int tmi = 0; tmi < 4; ++tmi) {
            const int mb = m0 + wm * 64 + tmi * 16 + qrow;
#pragma unroll
            for (int tni = 0; tni < 4; ++tni) {
                const int n = nbase + wn * 64 + tni * 16 + col;
                const float bvl = bias[n];
#pragma unroll
                for (int i = 0; i < 4; ++i) {
                    const float v = acc[tmi][tni][i] + bvl;
                    const u16 h = f2bf(v);
                    const long o = (long)(mb + i) * 1024 + n;
                    Ch[o] = h;
                    Cl[o] = f2bf(v - bf2f(h));
                }
            }
        }
    } else {
#pragma unroll
        for (int tmi = 0; tmi < 4; ++tmi) {
            const int mb = m0 + wm * 64 + tmi * 16 + qrow;
            const int bbv = mb / S, s = mb % S;
#pragma unroll
            for (int tni = 0; tni < 4; ++tni) {
                const int n = nbase + wn * 64 + tni * 16 + col;
                const float bvl = bv[n];
                u16 hv[4];
#pragma unroll
                for (int i = 0; i < 4; ++i) hv[i] = f2bf(acc[tmi][tni][i] + bvl);
                const long o = ((long)bbv * 1024 + n) * S + s;
                *(us4*)&vt[o] = (us4){hv[0], hv[1], hv[2], hv[3]};
            }
        }
    }
}

// ---------------------------------------------------------------------------
// Fused flash attention.  Q [b*Sq+s][1024] hi/lo planes; K [b*Sk+s][1024]
// hi/lo planes; Vt bf16 [b][1024][Sk]; mask fp32 [b][Sk].
// Block: 64 Q-rows (4 waves x 16 rows), K-tiles of 64. grid (1, Sq/64, B*H).
__global__ __launch_bounds__(256, 2)
void flash_attn(const u16* __restrict__ qh, const u16* __restrict__ ql,
                const u16* __restrict__ kh, const u16* __restrict__ kl,
                const u16* __restrict__ vt, const float* __restrict__ mask,
                float* __restrict__ out, int Sq, int Sk, float scale)
{
    __shared__ u16 lds[28672];        // 56 KB
    u16* KhL = lds;                   // [64][128]
    u16* KlL = lds + 8192;            // [64][128]
    u16* VtL = lds + 16384;           // [128][64]
    u16* PL  = lds + 24576;           // [64][64]
    u16* QhL = lds;                   // staging alias [64][128]
    u16* QlL = lds + 8192;

    const int b  = blockIdx.z >> 3, hd = blockIdx.z & 7;
    const int q0 = blockIdx.y * 64;
    const int lane = threadIdx.x & 63, w = threadIdx.x >> 6;
    const int col = lane & 15, quad = lane >> 4;

    // ---- stage Q (64x128) hi/lo, load fragments ----
    const long qoff = ((long)(b * Sq + q0)) * 1024 + hd * 128;
#pragma unroll
    for (int j = 0; j < 8; ++j) {
        const int cl = (j & 3) * 256 + w * 64 + lane;   // 0..1023
        const int row = cl >> 4, c16 = cl & 15;
        const u16* src = (j < 4) ? qh : ql;
        u16* dst = ((j < 4) ? QhL : QlL) + ((j & 3) * 256 + w * 64) * 8;
        GLL16(src + qoff + (long)row * 1024 + c16 * 8, dst);
    }
    __syncthreads();

    v8s qfh[4], qfl[4];
    const int qrow = w * 16 + col;    // A-frag m index
#pragma unroll
    for (int kf = 0; kf < 4; ++kf) {
        qfh[kf] = *(const v8s*)&QhL[qrow * 128 + kf * 32 + quad * 8];
        qfl[kf] = *(const v8s*)&QlL[qrow * 128 + kf * 32 + quad * 8];
    }

    v4f O[8];
#pragma unroll
    for (int nj = 0; nj < 8; ++nj) O[nj] = (v4f){0.f, 0.f, 0.f, 0.f};
    float m_r[4] = {-1e30f, -1e30f, -1e30f, -1e30f};
    float l_r[4] = {0.f, 0.f, 0.f, 0.f};

    const long kbase = (long)b * Sk * 1024 + hd * 128;
    const long vbase = ((long)b * 1024 + hd * 128) * Sk;
    const int nk = Sk >> 6;

    for (int kt = 0; kt < nk; ++kt) {
        __syncthreads();   // all waves done with Q-frags / prev K,V,P reads
        // ---- stage K-tile hi/lo (64x128) + Vt-tile (128x64) ----
#pragma unroll
        for (int j = 0; j < 12; ++j) {
            const int cl = (j & 3) * 256 + w * 64 + lane;   // 0..1023
            if (j < 8) {
                const int row = cl >> 4, c16 = cl & 15;
                const u16* src = (j < 4) ? kh : kl;
                u16* dst = ((j < 4) ? KhL : KlL) + cl * 8;
                GLL16(src + kbase + (long)(kt * 64 + row) * 1024 + c16 * 8, dst);
            } else {
                const int row = cl >> 3, c8 = cl & 7;
                GLL16(vt + vbase + (long)row * Sk + kt * 64 + c8 * 8, VtL + cl * 8);
            }
        }
        __syncthreads();

        // ---- S = Q K^T (split: hi*hi + hi*lo + lo*hi) ----
        v4f sa[4];
#pragma unroll
        for (int tn = 0; tn < 4; ++tn) sa[tn] = (v4f){0.f, 0.f, 0.f, 0.f};
#pragma unroll
        for (int kf = 0; kf < 4; ++kf) {
            v8s bh[4], bl[4];
#pragma unroll
            for (int tn = 0; tn < 4; ++tn) {
                const int off = (tn * 16 + col) * 128 + kf * 32 + quad * 8;
                bh[tn] = *(const v8s*)&KhL[off];
                bl[tn] = *(const v8s*)&KlL[off];
            }
#pragma unroll
            for (int tn = 0; tn < 4; ++tn) {
                sa[tn] = MFMA_BF16(qfh[kf], bh[tn], sa[tn], 0, 0, 0);
                sa[tn] = MFMA_BF16(qfh[kf], bl[tn], sa[tn], 0, 0, 0);
                sa[tn] = MFMA_BF16(qfl[kf], bh[tn], sa[tn], 0, 0, 0);
            }
        }

        // ---- online softmax (rows in quad*4+r, cols in lane&15 + tn*16) ----
        float sv[4][4];
#pragma unroll
        for (int tn = 0; tn < 4; ++tn) {
            const float mv = mask[b * Sk + kt * 64 + tn * 16 + col];
#pragma unroll
            for (int r = 0; r < 4; ++r) sv[tn][r] = sa[tn][r] * scale + mv;
        }
        float rowm[4], alpha[4], rs[4];
#pragma unroll
        for (int r = 0; r < 4; ++r)
            rowm[r] = fmaxf(fmaxf(sv[0][r], sv[1][r]), fmaxf(sv[2][r], sv[3][r]));
#pragma unroll
        for (int d = 1; d < 16; d <<= 1)
#pragma unroll
            for (int r = 0; r < 4; ++r)
                rowm[r] = fmaxf(rowm[r], __shfl_xor(rowm[r], d, 64));
#pragma unroll
        for (int r = 0; r < 4; ++r) {
            const float mnew = fmaxf(m_r[r], rowm[r]);
            alpha[r] = __expf(m_r[r] - mnew);
            m_r[r] = mnew;
            rs[r] = 0.f;
        }
        float p[4][4];
#pragma unroll
        for (int tn = 0; tn < 4; ++tn)
#pragma unroll
            for (int r = 0; r < 4; ++r) {
                p[tn][r] = __expf(sv[tn][r] - m_r[r]);
                rs[r] += p[tn][r];
            }
#pragma unroll
        for (int d = 1; d < 16; d <<= 1)
#pragma unroll
            for (int r = 0; r < 4; ++r) rs[r] += __shfl_xor(rs[r], d, 64);
#pragma unroll
        for (int r = 0; r < 4; ++r) l_r[r] = l_r[r] * alpha[r] + rs[r];
#pragma unroll
        for (int nj = 0; nj < 8; ++nj)
#pragma unroll
            for (int r = 0; r < 4; ++r) O[nj][r] *= alpha[r];

        // ---- P -> LDS (bf16), C-layout -> A-layout round trip ----
#pragma unroll
        for (int tn = 0; tn < 4; ++tn)
#pragma unroll
            for (int r = 0; r < 4; ++r)
                PL[(w * 16 + quad * 4 + r) * 64 + tn * 16 + col] = f2bf(p[tn][r]);
        __syncthreads();

        // ---- O += P @ V ----
#pragma unroll
        for (int kf2 = 0; kf2 < 2; ++kf2) {
            const v8s pa = *(const v8s*)&PL[(w * 16 + col) * 64 + kf2 * 32 + quad * 8];
#pragma unroll
            for (int nj = 0; nj < 8; ++nj) {
                const v8s vb = *(const v8s*)&VtL[(nj * 16 + col) * 64 + kf2 * 32 + quad * 8];
                O[nj] = MFMA_BF16(pa, vb, O[nj], 0, 0, 0);
            }
        }
    }

    // ---- epilogue: O /= l, write fp32 out [b*Sq+q][hd*128 + d] ----
    float inv[4];
#pragma unroll
    for (int r = 0; r < 4; ++r) inv[r] = 1.0f / l_r[r];
    const long obase = ((long)(b * Sq + q0 + w * 16 + quad * 4)) * 1024 + hd * 128;
#pragma unroll
    for (int nj = 0; nj < 8; ++nj)
#pragma unroll
        for (int r = 0; r < 4; ++r)
            out[obase + (long)r * 1024 + nj * 16 + col] = O[nj][r] * inv[r];
}

// ---------------------------------------------------------------------------
extern "C" void kernel_launch(void* const* d_in, const int* in_sizes, int n_in,
                              void* d_out, int out_size, void* d_ws, size_t ws_size,
                              hipStream_t stream)
{
    const float* in1   = (const float*)d_in[0];
    const float* mask1 = (const float*)d_in[1];
    const float* in2   = (const float*)d_in[2];
    const float* mask2 = (const float*)d_in[3];
    const float* Wq1 = (const float*)d_in[4];  const float* bq1 = (const float*)d_in[5];
    const float* Wk1 = (const float*)d_in[6];  const float* bk1 = (const float*)d_in[7];
    const float* Wv1 = (const float*)d_in[8];  const float* bv1 = (const float*)d_in[9];
    const float* Wq2 = (const float*)d_in[10]; const float* bq2 = (const float*)d_in[11];
    const float* Wk2 = (const float*)d_in[12]; const float* bk2 = (const float*)d_in[13];
    const float* Wv2 = (const float*)d_in[14]; const float* bv2 = (const float*)d_in[15];

    constexpr int Bb = 16, S1 = 256, S2 = 512, VH = 1024, TH = 768, H = 8;
    constexpr long M1 = (long)Bb * S1, M2 = (long)Bb * S2;
    const float scale = 0.088388347648318447f;   // 1/sqrt(128)

    // ---- workspace (u16 elements unless noted) ----
    char* W = (char*)d_ws;
    size_t o = 0;
    auto alloc = [&](size_t bytes) { size_t r = o; o = (o + bytes + 255) & ~(size_t)255; return r; };
    const size_t o_i1h = alloc(M1 * VH * 2), o_i1l = alloc(M1 * VH * 2);
    const size_t o_i2h = alloc(M2 * TH * 2), o_i2l = alloc(M2 * TH * 2);
    const size_t o_w1h = alloc((size_t)3072 * VH * 2), o_w1l = alloc((size_t)3072 * VH * 2);
    const size_t o_w2h = alloc((size_t)3072 * TH * 2), o_w2l = alloc((size_t)3072 * TH * 2);
    const size_t o_q2h = alloc(M2 * 1024 * 2), o_q2l = alloc(M2 * 1024 * 2);
    const size_t o_k1h = alloc(M1 * 1024 * 2), o_k1l = alloc(M1 * 1024 * 2);
    const size_t o_v1t = alloc(M1 * 1024 * 2);
    const size_t o_q1h = alloc(M1 * 1024 * 2), o_q1l = alloc(M1 * 1024 * 2);
    const size_t o_k2h = alloc(M2 * 1024 * 2), o_k2l = alloc(M2 * 1024 * 2);
    const size_t o_v2t = alloc(M2 * 1024 * 2);
    auto U = [&](size_t off) { return (u16*)(W + off); };
    float* out = (float*)d_out;

    // ---- converts ----
    cvt_split<<<dim3((unsigned)(M1 * VH / 1024)), 256, 0, stream>>>(in1, U(o_i1h), U(o_i1l), M1 * VH);
    cvt_split<<<dim3((unsigned)(M2 * TH / 1024)), 256, 0, stream>>>(in2, U(o_i2h), U(o_i2l), M2 * TH);
    cvt_split_T<<<dim3(16, 16), 256, 0, stream>>>(Wq1, U(o_w1h), U(o_w1l), VH, 1024);
    cvt_split_T<<<dim3(16, 16), 256, 0, stream>>>(Wk1, U(o_w1h) + (size_t)1024 * VH, U(o_w1l) + (size_t)1024 * VH, VH, 1024);
    cvt_split_T<<<dim3(16, 16), 256, 0, stream>>>(Wv1, U(o_w1h) + (size_t)2048 * VH, U(o_w1l) + (size_t)2048 * VH, VH, 1024);
    cvt_split_T<<<dim3(16, 12), 256, 0, stream>>>(Wq2, U(o_w2h), U(o_w2l), TH, 1024);
    cvt_split_T<<<dim3(16, 12), 256, 0, stream>>>(Wk2, U(o_w2h) + (size_t)1024 * TH, U(o_w2l) + (size_t)1024 * TH, TH, 1024);
    cvt_split_T<<<dim3(16, 12), 256, 0, stream>>>(Wv2, U(o_w2h) + (size_t)2048 * TH, U(o_w2l) + (size_t)2048 * TH, TH, 1024);

    // ---- projections (concat N=3072) ----
    mm_proj<<<dim3(24, 32, 1), 256, 0, stream>>>(
        U(o_i1h), U(o_i1l), U(o_w1h), U(o_w1l), bq1, bk1, bv1,
        U(o_q1h), U(o_q1l), U(o_k1h), U(o_k1l), U(o_v1t), VH, S1);
    mm_proj<<<dim3(24, 64, 1), 256, 0, stream>>>(
        U(o_i2h), U(o_i2l), U(o_w2h), U(o_w2l), bq2, bk2, bv2,
        U(o_q2h), U(o_q2l), U(o_k2h), U(o_k2l), U(o_v2t), TH, S2);

    // ---- fused attention ----
    // context1: q2 (Sq=512) attends k1/v1 (Sk=256)
    flash_attn<<<dim3(1, S2 / 64, Bb * H), 256, 0, stream>>>(
        U(o_q2h), U(o_q2l), U(o_k1h), U(o_k1l), U(o_v1t), mask1,
        out, S2, S1, scale);
    // context2: q1 (Sq=256) attends k2/v2 (Sk=512)
    flash_attn<<<dim3(1, S1 / 64, Bb * H), 256, 0, stream>>>(
        U(o_q1h), U(o_q1l), U(o_k2h), U(o_k2l), U(o_v2t), mask2,
        out + M2 * 1024, S1, S2, scale);
}

// Round 4
// 285.644 us; speedup vs baseline: 4.6968x; 1.6477x over previous
//
#include <hip/hip_runtime.h>

// ---------------------------------------------------------------------------
// BertBiAttention, all-fp16 MFMA path (fp32 accumulate everywhere).
//  - 2 projection GEMMs (concat q|k|v weights, N=3072), m97-shape K-loop.
//  - fused flash attention, XOR-swizzled LDS chunks (conflict-free frag reads
//    while keeping global_load_lds lane-linear dests).
// ---------------------------------------------------------------------------

typedef _Float16 f16;
typedef unsigned int u32;
typedef f16  v8h __attribute__((ext_vector_type(8)));   // 8 fp16 (4 VGPRs)
typedef float v4f __attribute__((ext_vector_type(4)));  // MFMA acc

struct alignas(8) h4 { f16 x, y, z, w; };

#define GLL16(g, l) __builtin_amdgcn_global_load_lds(                          \
    (const __attribute__((address_space(1))) u32*)(g),                         \
    (__attribute__((address_space(3))) u32*)(l), 16, 0, 0)

#define MFMA16 __builtin_amdgcn_mfma_f32_16x16x32_f16

// ---------------------------------------------------------------------------
// fp32 -> fp16 for both input tensors in one launch
__global__ __launch_bounds__(256)
void cvt_in(const float* __restrict__ p1, long n1,
            const float* __restrict__ p2, long n2,
            f16* __restrict__ d1, f16* __restrict__ d2)
{
    long i = ((long)blockIdx.x * 256 + threadIdx.x) * 8;
    const float* s; f16* d;
    if (i < n1) { s = p1 + i; d = d1 + i; }
    else        { long j = i - n1; if (j >= n2) return; s = p2 + j; d = d2 + j; }
    float4 a = *(const float4*)s, b = *(const float4*)(s + 4);
    v8h o = {(f16)a.x, (f16)a.y, (f16)a.z, (f16)a.w,
             (f16)b.x, (f16)b.y, (f16)b.z, (f16)b.w};
    *(v8h*)d = o;
}

// all 6 weights: fp32 [K][1024] -> fp16 [1024][K], concatenated per stream
__global__ __launch_bounds__(256)
void cvt_wT(const float* __restrict__ w0, const float* __restrict__ w1,
            const float* __restrict__ w2, const float* __restrict__ w3,
            const float* __restrict__ w4, const float* __restrict__ w5,
            f16* __restrict__ o1, f16* __restrict__ o2)
{
    const int z = blockIdx.z;
    const int K = z < 3 ? 1024 : 768;
    const int bk = blockIdx.y * 64;
    if (bk >= K) return;
    const float* src = z == 0 ? w0 : z == 1 ? w1 : z == 2 ? w2
                     : z == 3 ? w3 : z == 4 ? w4 : w5;
    f16* dst = z < 3 ? o1 + (size_t)z * 1024 * 1024
                     : o2 + (size_t)(z - 3) * 1024 * 768;

    __shared__ float t[64][65];
    const int bn = blockIdx.x * 64;
    const int r0 = threadIdx.x >> 4, c4 = (threadIdx.x & 15) * 4;
#pragma unroll
    for (int rr = 0; rr < 64; rr += 16) {
        float4 v = *(const float4*)&src[(long)(bk + rr + r0) * 1024 + bn + c4];
        t[rr + r0][c4 + 0] = v.x; t[rr + r0][c4 + 1] = v.y;
        t[rr + r0][c4 + 2] = v.z; t[rr + r0][c4 + 3] = v.w;
    }
    __syncthreads();
#pragma unroll
    for (int rr = 0; rr < 64; rr += 16) {
        const int n = rr + r0;
        h4 o = {(f16)t[c4 + 0][n], (f16)t[c4 + 1][n],
                (f16)t[c4 + 2][n], (f16)t[c4 + 3][n]};
        *(h4*)&dst[(long)(bn + n) * K + bk + c4] = o;
    }
}

// ---------------------------------------------------------------------------
// Projection GEMM (fp16, m97 shape): A [M][K], Bw [3072][K] (q|k|v concat).
// seg = n0>>10: 0 -> q [M][1024]; 1 -> k [M][1024]; 2 -> v transposed
// [b][1024][S] (S = rows per batch).
__global__ __launch_bounds__(256, 2)
void mm_proj(const f16* __restrict__ A, const f16* __restrict__ Bw,
             const float* __restrict__ bq, const float* __restrict__ bk,
             const float* __restrict__ bv,
             f16* __restrict__ qo, f16* __restrict__ ko, f16* __restrict__ vo,
             int K, int S)
{
    __shared__ f16 As[128 * 32], Bs[128 * 32];
    const int m0 = blockIdx.y * 128, n0 = blockIdx.x * 128;
    const int tid = threadIdx.x, lane = tid & 63, w = tid >> 6;
    const int wm = w >> 1, wn = w & 1;

    v4f acc[4][4];
#pragma unroll
    for (int i = 0; i < 4; ++i)
#pragma unroll
        for (int j = 0; j < 4; ++j) acc[i][j] = (v4f){0.f, 0.f, 0.f, 0.f};

    for (int k0 = 0; k0 < K; k0 += 32) {
#pragma unroll
        for (int j = 0; j < 2; ++j) {        // A tile: 128 rows x 32 halves
            const int c = j * 256 + tid, row = c >> 2, kc = c & 3;
            GLL16(A + (long)(m0 + row) * K + k0 + kc * 8, As + c * 8);
        }
#pragma unroll
        for (int j = 0; j < 2; ++j) {        // B tile
            const int c = j * 256 + tid, row = c >> 2, kc = c & 3;
            GLL16(Bw + (long)(n0 + row) * K + k0 + kc * 8, Bs + c * 8);
        }
        __syncthreads();

        const int fr = lane & 15, fq = lane >> 4;
        v8h ah[4], bh[4];
#pragma unroll
        for (int tmi = 0; tmi < 4; ++tmi)
            ah[tmi] = *(const v8h*)&As[(wm * 64 + tmi * 16 + fr) * 32 + fq * 8];
#pragma unroll
        for (int tni = 0; tni < 4; ++tni)
            bh[tni] = *(const v8h*)&Bs[(wn * 64 + tni * 16 + fr) * 32 + fq * 8];
#pragma unroll
        for (int tmi = 0; tmi < 4; ++tmi)
#pragma unroll
            for (int tni = 0; tni < 4; ++tni)
                acc[tmi][tni] = MFMA16(ah[tmi], bh[tni], acc[tmi][tni], 0, 0, 0);
        __syncthreads();
    }

    // epilogue; C layout: col = lane&15, row = quad*4 + reg
    const int col = lane & 15, qrow = (lane >> 4) * 4;
    const int seg = n0 >> 10, nbase = n0 & 1023;

    if (seg < 2) {
        const float* bias = seg == 0 ? bq : bk;
        f16* Co = seg == 0 ? qo : ko;
#pragma unroll
        for (int tmi = 0; tmi < 4; ++tmi) {
            const int mb = m0 + wm * 64 + tmi * 16 + qrow;
#pragma unroll
            for (int tni = 0; tni < 4; ++tni) {
                const int n = nbase + wn * 64 + tni * 16 + col;
                const float bvl = bias[n];
#pragma unroll
                for (int i = 0; i < 4; ++i)
                    Co[(long)(mb + i) * 1024 + n] = (f16)(acc[tmi][tni][i] + bvl);
            }
        }
    } else {
#pragma unroll
        for (int tmi = 0; tmi < 4; ++tmi) {
            const int mb = m0 + wm * 64 + tmi * 16 + qrow;
            const int bb = mb / S, s = mb % S;
#pragma unroll
            for (int tni = 0; tni < 4; ++tni) {
                const int n = nbase + wn * 64 + tni * 16 + col;
                const float bvl = bv[n];
                h4 o = {(f16)(acc[tmi][tni][0] + bvl), (f16)(acc[tmi][tni][1] + bvl),
                        (f16)(acc[tmi][tni][2] + bvl), (f16)(acc[tmi][tni][3] + bvl)};
                *(h4*)&vo[((long)bb * 1024 + n) * S + s] = o;
            }
        }
    }
}

// ---------------------------------------------------------------------------
// Fused flash attention, fp16.  Q/K: [b*S+s][1024] (head cols hd*128..);
// Vt: [b][1024][Sk]; mask fp32 [b][Sk].  Block = RT*64 Q-rows (4 waves x RT
// 16-row frags), K-tiles of 64.  LDS chunks XOR-swizzled: logical 16B chunk
// `ch` of row r is stored at physical slot ch^(r&15) (K/Q, 16 chunks/row) or
// ch^(r&7) (V, 8 chunks/row) -> frag reads conflict-free, GLL dests linear.
template<int RT>
__global__ __launch_bounds__(256, 2)
void flash(const f16* __restrict__ qp, const f16* __restrict__ kp,
           const f16* __restrict__ vp, const float* __restrict__ mask,
           float* __restrict__ out, int Sq, int Sk, float scale)
{
    constexpr int PSTR = 72;                    // P row stride (pad 8)
    __shared__ f16 lds[16384 + RT * 64 * PSTR];
    f16* KL = lds;                              // [64][128] swizzled
    f16* VL = lds + 8192;                       // [128][64] swizzled
    f16* PL = lds + 16384;                      // [RT*64][72]
    f16* QL = lds;                              // Q staging alias (<=16384)

    const int b = blockIdx.z >> 3, hd = blockIdx.z & 7;
    const int q0 = blockIdx.y * (RT * 64);
    const int tid = threadIdx.x, lane = tid & 63, w = tid >> 6;
    const int col = lane & 15, quad = lane >> 4;

    // ---- stage Q (RT*64 x 128), source-swizzled ----
    const long qoff = ((long)b * Sq + q0) * 1024 + (long)hd * 128;
#pragma unroll
    for (int j = 0; j < RT * 4; ++j) {
        const int c = j * 256 + tid, row = c >> 4, ch = (c & 15) ^ (row & 15);
        GLL16(qp + qoff + (long)row * 1024 + ch * 8, QL + c * 8);
    }
    __syncthreads();
    v8h qf[RT][4];
#pragma unroll
    for (int rt = 0; rt < RT; ++rt) {
        const int row = w * (RT * 16) + rt * 16 + col;
#pragma unroll
        for (int kf = 0; kf < 4; ++kf)
            qf[rt][kf] = *(const v8h*)&QL[row * 128 + ((kf * 4 + quad) ^ (row & 15)) * 8];
    }

    v4f O[RT][8];
    float m_r[RT][4], l_r[RT][4];
#pragma unroll
    for (int rt = 0; rt < RT; ++rt) {
#pragma unroll
        for (int nj = 0; nj < 8; ++nj) O[rt][nj] = (v4f){0.f, 0.f, 0.f, 0.f};
#pragma unroll
        for (int r = 0; r < 4; ++r) { m_r[rt][r] = -1e30f; l_r[rt][r] = 0.f; }
    }

    const long kbase = (long)b * Sk * 1024 + (long)hd * 128;
    const long vbase = ((long)b * 1024 + hd * 128) * (long)Sk;

    for (int kt = 0; kt < (Sk >> 6); ++kt) {
        __syncthreads();                        // prev-tile reads (and Q) done
#pragma unroll
        for (int j = 0; j < 4; ++j) {           // K tile 64x128
            const int c = j * 256 + tid, row = c >> 4, ch = (c & 15) ^ (row & 15);
            GLL16(kp + kbase + (long)(kt * 64 + row) * 1024 + ch * 8, KL + c * 8);
        }
#pragma unroll
        for (int j = 0; j < 4; ++j) {           // V tile 128x64 (transposed src)
            const int c = j * 256 + tid, row = c >> 3, ch = (c & 7) ^ (row & 7);
            GLL16(vp + vbase + (long)row * Sk + kt * 64 + ch * 8, VL + c * 8);
        }
        __syncthreads();

        // ---- S = Q K^T ----
        v4f sa[RT][4];
#pragma unroll
        for (int rt = 0; rt < RT; ++rt)
#pragma unroll
            for (int tn = 0; tn < 4; ++tn) sa[rt][tn] = (v4f){0.f, 0.f, 0.f, 0.f};
#pragma unroll
        for (int kf = 0; kf < 4; ++kf) {
            v8h bh[4];
#pragma unroll
            for (int tn = 0; tn < 4; ++tn) {
                const int row = tn * 16 + col;
                bh[tn] = *(const v8h*)&KL[row * 128 + ((kf * 4 + quad) ^ (row & 15)) * 8];
            }
#pragma unroll
            for (int rt = 0; rt < RT; ++rt)
#pragma unroll
                for (int tn = 0; tn < 4; ++tn)
                    sa[rt][tn] = MFMA16(qf[rt][kf], bh[tn], sa[rt][tn], 0, 0, 0);
        }

        // ---- online softmax (row = quad*4+r, col = tn*16 + lane&15) ----
        float mv[4];
#pragma unroll
        for (int tn = 0; tn < 4; ++tn)
            mv[tn] = mask[(long)b * Sk + kt * 64 + tn * 16 + col];
#pragma unroll
        for (int rt = 0; rt < RT; ++rt) {
            float sv[4][4], rowm[4], alpha[4], rs[4], p[4][4];
#pragma unroll
            for (int tn = 0; tn < 4; ++tn)
#pragma unroll
                for (int r = 0; r < 4; ++r) sv[tn][r] = sa[rt][tn][r] * scale + mv[tn];
#pragma unroll
            for (int r = 0; r < 4; ++r)
                rowm[r] = fmaxf(fmaxf(sv[0][r], sv[1][r]), fmaxf(sv[2][r], sv[3][r]));
#pragma unroll
            for (int d = 1; d < 16; d <<= 1)
#pragma unroll
                for (int r = 0; r < 4; ++r)
                    rowm[r] = fmaxf(rowm[r], __shfl_xor(rowm[r], d, 64));
#pragma unroll
            for (int r = 0; r < 4; ++r) {
                const float mnew = fmaxf(m_r[rt][r], rowm[r]);
                alpha[r] = __expf(m_r[rt][r] - mnew);
                m_r[rt][r] = mnew;
                rs[r] = 0.f;
            }
#pragma unroll
            for (int tn = 0; tn < 4; ++tn)
#pragma unroll
                for (int r = 0; r < 4; ++r) {
                    p[tn][r] = __expf(sv[tn][r] - m_r[rt][r]);
                    rs[r] += p[tn][r];
                }
#pragma unroll
            for (int d = 1; d < 16; d <<= 1)
#pragma unroll
                for (int r = 0; r < 4; ++r) rs[r] += __shfl_xor(rs[r], d, 64);
#pragma unroll
            for (int r = 0; r < 4; ++r) l_r[rt][r] = l_r[rt][r] * alpha[r] + rs[r];
#pragma unroll
            for (int nj = 0; nj < 8; ++nj)
#pragma unroll
                for (int r = 0; r < 4; ++r) O[rt][nj][r] *= alpha[r];
#pragma unroll
            for (int tn = 0; tn < 4; ++tn)
#pragma unroll
                for (int r = 0; r < 4; ++r)
                    PL[(w * RT * 16 + rt * 16 + quad * 4 + r) * PSTR + tn * 16 + col]
                        = (f16)p[tn][r];
        }

        // ---- O += P @ V (P rows are wave-private: no barrier needed) ----
#pragma unroll
        for (int kf2 = 0; kf2 < 2; ++kf2) {
            v8h vb[8];
#pragma unroll
            for (int nj = 0; nj < 8; ++nj) {
                const int row = nj * 16 + col;
                vb[nj] = *(const v8h*)&VL[row * 64 + ((kf2 * 4 + quad) ^ (row & 7)) * 8];
            }
#pragma unroll
            for (int rt = 0; rt < RT; ++rt) {
                const v8h pa = *(const v8h*)&PL[(w * RT * 16 + rt * 16 + col) * PSTR
                                                + kf2 * 32 + quad * 8];
#pragma unroll
                for (int nj = 0; nj < 8; ++nj)
                    O[rt][nj] = MFMA16(pa, vb[nj], O[rt][nj], 0, 0, 0);
            }
        }
    }

    // ---- epilogue ----
#pragma unroll
    for (int rt = 0; rt < RT; ++rt) {
        float inv[4];
#pragma unroll
        for (int r = 0; r < 4; ++r) inv[r] = 1.0f / l_r[rt][r];
        const long ob = ((long)b * Sq + q0 + w * (RT * 16) + rt * 16 + quad * 4) * 1024
                        + (long)hd * 128;
#pragma unroll
        for (int nj = 0; nj < 8; ++nj)
#pragma unroll
            for (int r = 0; r < 4; ++r)
                out[ob + (long)r * 1024 + nj * 16 + col] = O[rt][nj][r] * inv[r];
    }
}

// ---------------------------------------------------------------------------
extern "C" void kernel_launch(void* const* d_in, const int* in_sizes, int n_in,
                              void* d_out, int out_size, void* d_ws, size_t ws_size,
                              hipStream_t stream)
{
    const float* in1   = (const float*)d_in[0];
    const float* mask1 = (const float*)d_in[1];
    const float* in2   = (const float*)d_in[2];
    const float* mask2 = (const float*)d_in[3];
    const float* Wq1 = (const float*)d_in[4];  const float* bq1 = (const float*)d_in[5];
    const float* Wk1 = (const float*)d_in[6];  const float* bk1 = (const float*)d_in[7];
    const float* Wv1 = (const float*)d_in[8];  const float* bv1 = (const float*)d_in[9];
    const float* Wq2 = (const float*)d_in[10]; const float* bq2 = (const float*)d_in[11];
    const float* Wk2 = (const float*)d_in[12]; const float* bk2 = (const float*)d_in[13];
    const float* Wv2 = (const float*)d_in[14]; const float* bv2 = (const float*)d_in[15];

    constexpr int Bb = 16, S1 = 256, S2 = 512, VH = 1024, TH = 768;
    constexpr long M1 = (long)Bb * S1, M2 = (long)Bb * S2;
    const float scale = 0.088388347648318447f;   // 1/sqrt(128)

    // ---- workspace (fp16 elements) ----
    f16* W = (f16*)d_ws;
    f16* i1  = W;                        // [4096][1024]
    f16* i2  = i1 + M1 * VH;             // [8192][768]
    f16* w1  = i2 + M2 * TH;             // [3072][1024]
    f16* w2  = w1 + (long)3072 * VH;     // [3072][768]
    f16* q1  = w2 + (long)3072 * TH;     // [4096][1024]
    f16* k1  = q1 + M1 * 1024;
    f16* v1t = k1 + M1 * 1024;           // [16][1024][256]
    f16* q2  = v1t + M1 * 1024;          // [8192][1024]
    f16* k2  = q2 + M2 * 1024;
    f16* v2t = k2 + M2 * 1024;           // [16][1024][512]
    float* out = (float*)d_out;

    // ---- converts (2 launches) ----
    cvt_in<<<dim3(5120), 256, 0, stream>>>(in1, M1 * VH, in2, M2 * TH, i1, i2);
    cvt_wT<<<dim3(16, 16, 6), 256, 0, stream>>>(Wq1, Wk1, Wv1, Wq2, Wk2, Wv2, w1, w2);

    // ---- projections ----
    mm_proj<<<dim3(24, 32), 256, 0, stream>>>(i1, w1, bq1, bk1, bv1,
                                              q1, k1, v1t, VH, S1);
    mm_proj<<<dim3(24, 64), 256, 0, stream>>>(i2, w2, bq2, bk2, bv2,
                                              q2, k2, v2t, TH, S2);

    // ---- fused attention ----
    // context1: q2 (Sq=512, 128-row Q-tiles) vs k1/v1 (Sk=256)
    flash<2><<<dim3(1, 4, 128), 256, 0, stream>>>(q2, k1, v1t, mask1,
                                                  out, S2, S1, scale);
    // context2: q1 (Sq=256, 64-row Q-tiles) vs k2/v2 (Sk=512)
    flash<1><<<dim3(1, 4, 128), 256, 0, stream>>>(q1, k2, v2t, mask2,
                                                  out + M2 * 1024, S1, S2, scale);
}